// Round 5
// baseline (766.381 us; speedup 1.0000x reference)
//
#include <hip/hip_runtime.h>

typedef __attribute__((ext_vector_type(8))) short short8;
typedef __attribute__((ext_vector_type(4))) float floatx4;
typedef unsigned int u32;

#define DIM 384
#define NHEAD 12
#define HDIM 32

__device__ __forceinline__ float bf2f(unsigned int u) {
    union { unsigned int i; float f; } x; x.i = (u & 0xffffu) << 16; return x.f;
}
__device__ __forceinline__ unsigned short f2bf(float f) {
    union { float f; unsigned int i; } x; x.f = f;
    return (unsigned short)((x.i + 0x7fffu + ((x.i >> 16) & 1u)) >> 16);
}

__device__ __forceinline__ int nat2win(int r) {
    int b = r / 3136; int l = r - b * 3136;
    int hh = l / 56, wc = l - hh * 56;
    int wh = hh / 7, nr = hh - wh * 7;
    int ww = wc / 7, nc = wc - ww * 7;
    return ((b << 6) + wh * 8 + ww) * 49 + nr * 7 + nc;
}
__device__ __forceinline__ int win2nat(int r) {
    int w = r / 49; int n = r - w * 49;
    int b = w >> 6; int wi = w & 63;
    int wh = wi >> 3, ww = wi & 7;
    int hh = wh * 7 + n / 7, wc = ww * 7 + n % 7;
    return b * 3136 + hh * 56 + wc;
}

#define GLOAD_LDS16(g, l) \
    __builtin_amdgcn_global_load_lds((const __attribute__((address_space(1))) u32*)(g), \
                                     (__attribute__((address_space(3))) u32*)(l), 16, 0, 0)

__global__ void transpose_kernel(const float* __restrict__ src,
                                 unsigned short* __restrict__ dst,
                                 int K, int N, int ld) {
    int i = blockIdx.x * blockDim.x + threadIdx.x;
    if (i >= K * N) return;
    int n = i / K, k = i - n * K;
    dst[i] = f2bf(src[(size_t)k * ld + n]);
}

__global__ void bias_expand_kernel(const int* __restrict__ rel_index,
                                   const float* __restrict__ bias_table,
                                   float* __restrict__ biasx) {
    int i = blockIdx.x * blockDim.x + threadIdx.x;
    if (i >= NHEAD * 49 * 49) return;
    int h = i / 2401, r = i - h * 2401;
    biasx[i] = bias_table[rel_index[r] * NHEAD + h];
}

// LayerNorm over 384, fp32 in -> bf16 out; one wave per row.
__global__ __launch_bounds__(64) void ln_kernel(const float* __restrict__ x,
                                                const float* __restrict__ g,
                                                const float* __restrict__ b,
                                                unsigned short* __restrict__ out,
                                                int windowed) {
    int r = blockIdx.x;
    int lane = threadIdx.x;
    const float* row = x + (size_t)r * DIM;
    float v[6];
    float s = 0.f, ss = 0.f;
#pragma unroll
    for (int j = 0; j < 3; j++) {
        int c = lane + j * 64;
        float2 f = *(const float2*)(row + 2 * c);
        v[2 * j] = f.x; v[2 * j + 1] = f.y;
        s += f.x + f.y; ss += f.x * f.x + f.y * f.y;
    }
#pragma unroll
    for (int m = 1; m < 64; m <<= 1) {
        s += __shfl_xor(s, m);
        ss += __shfl_xor(ss, m);
    }
    float mean = s * (1.f / DIM);
    float var = ss * (1.f / DIM) - mean * mean;
    float rstd = rsqrtf(var + 1e-5f);
    int orow = windowed ? nat2win(r) : r;
    unsigned short* op = out + (size_t)orow * DIM;
#pragma unroll
    for (int j = 0; j < 3; j++) {
        int c = lane + j * 64;
        float2 gg = *(const float2*)(g + 2 * c);
        float2 bb = *(const float2*)(b + 2 * c);
        float o0 = (v[2 * j] - mean) * rstd * gg.x + bb.x;
        float o1 = (v[2 * j + 1] - mean) * rstd * gg.y + bb.y;
        unsigned int w = ((unsigned int)f2bf(o1) << 16) | f2bf(o0);
        *(unsigned int*)(op + 2 * c) = w;
    }
}

// MFMA attention: block = (image b, head h, group of 16 windows).
__global__ __launch_bounds__(256) void attn_kernel(const unsigned short* __restrict__ q,
                                                   const float* __restrict__ kv,
                                                   const float* __restrict__ biasx,
                                                   unsigned short* __restrict__ o) {
    __shared__ alignas(16) unsigned short Ks[64 * 40];
    __shared__ alignas(16) unsigned short Vt[32 * 72];
    __shared__ float Bi[49 * 52];
    __shared__ alignas(16) unsigned short Ps[4][16 * 72];

    int blk = blockIdx.x;
    int b = blk / 48; int rem = blk - b * 48;
    int h = rem >> 2; int g = rem & 3;
    size_t row_base = (size_t)(b * 64 + g * 16) * 49;

    int t = threadIdx.x;
    int lane = t & 63;
    int wv = t >> 6;
    int lr = lane & 15;
    int lg = lane >> 4;

    const float* kptr = kv + (size_t)(b * NHEAD + h) * 1568;
    for (int idx = t; idx < 392; idx += 256) {
        int row = idx >> 3, seg = idx & 7;
        float4 f = *(const float4*)(kptr + row * 32 + seg * 4);
        ushort4 h4; h4.x = f2bf(f.x); h4.y = f2bf(f.y); h4.z = f2bf(f.z); h4.w = f2bf(f.w);
        *(ushort4*)&Ks[row * 40 + seg * 4] = h4;
    }
    const float* vptr = kv + (size_t)(192 + b * NHEAD + h) * 1568;
    for (int idx = t; idx < 784; idx += 256) {
        int m = idx >> 4, dp = idx & 15;
        float2 f = *(const float2*)(vptr + m * 32 + dp * 2);
        Vt[(2 * dp) * 72 + m]     = f2bf(f.x);
        Vt[(2 * dp + 1) * 72 + m] = f2bf(f.y);
    }
    for (int idx = t; idx < 32 * 23; idx += 256) {
        int d = idx / 23, m = 49 + idx - d * 23;
        Vt[d * 72 + m] = 0;
    }
    const float* bh = biasx + h * 2401;
    for (int idx = t; idx < 2401; idx += 256) {
        int qr = idx / 49, k = idx - qr * 49;
        Bi[qr * 52 + k] = bh[idx];
    }
    __syncthreads();

    short8 bfr[4], vbf[2][2];
#pragma unroll
    for (int ni = 0; ni < 4; ni++)
        bfr[ni] = *(const short8*)&Ks[(ni * 16 + lr) * 40 + lg * 8];
#pragma unroll
    for (int ni = 0; ni < 2; ni++)
#pragma unroll
        for (int ks = 0; ks < 2; ks++)
            vbf[ni][ks] = *(const short8*)&Vt[(ni * 16 + lr) * 72 + ks * 32 + lg * 8];

    const unsigned short* qb = q + row_base * DIM + h * 32 + lg * 8;
    unsigned short* ob = o + row_base * DIM + h * 32;

    short8 af = *(const short8*)(qb + (size_t)(wv * 16 + lr) * DIM);
    for (int tm = wv; tm < 49; tm += 4) {
        short8 af_next;
        if (tm + 4 < 49) af_next = *(const short8*)(qb + (size_t)((tm + 4) * 16 + lr) * DIM);

        floatx4 sfrag[4];
#pragma unroll
        for (int ni = 0; ni < 4; ni++)
            sfrag[ni] = __builtin_amdgcn_mfma_f32_16x16x32_bf16(af, bfr[ni], (floatx4)0.f, 0, 0, 0);

#pragma unroll
        for (int reg = 0; reg < 4; reg++) {
            int r_loc = tm * 16 + lg * 4 + reg;
            int qr = r_loc % 49;
            float mx = -1e30f;
#pragma unroll
            for (int ni = 0; ni < 4; ni++) {
                int k = ni * 16 + lr;
                float s = sfrag[ni][reg];
                if (k < 49) s += Bi[qr * 52 + k];
                else s = -1e30f;
                sfrag[ni][reg] = s;
                mx = fmaxf(mx, s);
            }
#pragma unroll
            for (int j = 1; j < 16; j <<= 1) mx = fmaxf(mx, __shfl_xor(mx, j));
            float sum = 0.f;
#pragma unroll
            for (int ni = 0; ni < 4; ni++) {
                float e = __expf(sfrag[ni][reg] - mx);
                sfrag[ni][reg] = e;
                sum += e;
            }
#pragma unroll
            for (int j = 1; j < 16; j <<= 1) sum += __shfl_xor(sum, j);
            float inv = 1.f / sum;
#pragma unroll
            for (int ni = 0; ni < 4; ni++)
                Ps[wv][(lg * 4 + reg) * 72 + ni * 16 + lr] = f2bf(sfrag[ni][reg] * inv);
        }
        floatx4 ofrag[2] = {(floatx4)0.f, (floatx4)0.f};
#pragma unroll
        for (int ks = 0; ks < 2; ks++) {
            short8 paf = *(const short8*)&Ps[wv][lr * 72 + ks * 32 + lg * 8];
#pragma unroll
            for (int ni = 0; ni < 2; ni++)
                ofrag[ni] = __builtin_amdgcn_mfma_f32_16x16x32_bf16(paf, vbf[ni][ks], ofrag[ni], 0, 0, 0);
        }
#pragma unroll
        for (int reg = 0; reg < 4; reg++) {
            size_t rg = (size_t)(tm * 16 + lg * 4 + reg) * DIM;
#pragma unroll
            for (int ni = 0; ni < 2; ni++)
                ob[rg + ni * 16 + lr] = f2bf(ofrag[ni][reg]);
        }
        af = af_next;
    }
}

// C[M,N] = A[M,K](bf16) @ Bt[N,K](bf16)^T ; BK=64, XOR-swizzled LDS,
// XCD-aware block swizzle (1-D grid, nxt x nyt tiles, nyt%8==0 -> same-A-band
// tiles stay on one XCD's L2).
template <int BN, int DO_GELU, int DO_REMAP, int OUT_BF16>
__global__ __launch_bounds__(256) void gemm_kernel(const unsigned short* __restrict__ A,
                                                   const unsigned short* __restrict__ Bt,
                                                   const float* __restrict__ bias,
                                                   const float* __restrict__ res,
                                                   void* __restrict__ outv,
                                                   int M, int N, int K, float scale,
                                                   int nxt, int nyt) {
    constexpr int NF = BN / 32;           // n-frags per wave
    __shared__ alignas(16) unsigned short As[128 * 64];
    __shared__ alignas(16) unsigned short Bs[BN * 64];

    int lin = blockIdx.x;
    int m_t, n_t;
    if ((nyt & 7) == 0) {
        int xcd = lin & 7, slot = lin >> 3;
        int bands = nyt >> 3;
        int qq = slot / nxt;
        m_t = xcd * bands + qq;
        n_t = slot - qq * nxt;
    } else {
        n_t = lin % nxt; m_t = lin / nxt;
    }
    int m0 = m_t * 128;
    int n0 = n_t * BN;

    int t = threadIdx.x;
    int lane = t & 63;
    int wv = t >> 6;
    int wm = (wv >> 1) * 64, wn = (wv & 1) * (BN / 2);
    int lr = lane & 15;
    int lq = lane >> 4;

    int rowB = t >> 3;
    int colOff = (((t & 7) ^ ((t >> 3) & 7)) << 3);
    int sw0 = ((lq ^ (lr & 7)) << 3);
    int sw1 = (((4 + lq) ^ (lr & 7)) << 3);

    floatx4 acc[4][NF];
#pragma unroll
    for (int i = 0; i < 4; i++)
#pragma unroll
        for (int j = 0; j < NF; j++) acc[i][j] = (floatx4)0.f;

    for (int k0 = 0; k0 < K; k0 += 64) {
#pragma unroll
        for (int i = 0; i < 4; i++) {
            int row = i * 32 + rowB;
            GLOAD_LDS16(A + (size_t)(m0 + row) * K + k0 + colOff, &As[(i * 256 + t) * 8]);
        }
#pragma unroll
        for (int i = 0; i < BN / 32; i++) {
            int row = i * 32 + rowB;
            GLOAD_LDS16(Bt + (size_t)(n0 + row) * K + k0 + colOff, &Bs[(i * 256 + t) * 8]);
        }
        __syncthreads();
#pragma unroll
        for (int ksub = 0; ksub < 2; ksub++) {
            int sw = ksub ? sw1 : sw0;
            short8 af[4], bfr[NF];
#pragma unroll
            for (int i = 0; i < 4; i++)
                af[i] = *(const short8*)(&As[(wm + i * 16 + lr) * 64 + sw]);
#pragma unroll
            for (int j = 0; j < NF; j++)
                bfr[j] = *(const short8*)(&Bs[(wn + j * 16 + lr) * 64 + sw]);
#pragma unroll
            for (int i = 0; i < 4; i++)
#pragma unroll
                for (int j = 0; j < NF; j++)
                    acc[i][j] = __builtin_amdgcn_mfma_f32_16x16x32_bf16(af[i], bfr[j], acc[i][j], 0, 0, 0);
        }
        __syncthreads();
    }

#pragma unroll
    for (int j = 0; j < NF; j++) {
        int gcol = n0 + wn + j * 16 + lr;
        float bv = bias[gcol];
#pragma unroll
        for (int i = 0; i < 4; i++) {
#pragma unroll
            for (int r = 0; r < 4; r++) {
                int grow = m0 + wm + i * 16 + lq * 4 + r;
                float val = acc[i][j][r] + bv;
                if (DO_GELU) val = 0.5f * val * (1.f + erff(val * 0.70710678118654752f));
                val *= scale;
                int orow = DO_REMAP ? win2nat(grow) : grow;
                size_t idx = (size_t)orow * N + gcol;
                if (res) val += res[idx];
                if (OUT_BF16) ((unsigned short*)outv)[idx] = f2bf(val);
                else          ((float*)outv)[idx] = val;
            }
        }
    }
}

extern "C" void kernel_launch(void* const* d_in, const int* in_sizes, int n_in,
                              void* d_out, int out_size, void* d_ws, size_t ws_size,
                              hipStream_t stream) {
    const float* x          = (const float*)d_in[0];
    const float* kv         = (const float*)d_in[1];
    const int*   rel_index  = (const int*)d_in[2];
    const float* g1         = (const float*)d_in[5];
    const float* b1         = (const float*)d_in[6];
    const float* Wqkv       = (const float*)d_in[7];
    const float* bqkv       = (const float*)d_in[8];
    const float* bias_table = (const float*)d_in[9];
    const float* Wproj      = (const float*)d_in[10];
    const float* bproj      = (const float*)d_in[11];
    const float* g2         = (const float*)d_in[12];
    const float* b2         = (const float*)d_in[13];
    const float* Wfc1       = (const float*)d_in[14];
    const float* bfc1       = (const float*)d_in[15];
    const float* Wfc2       = (const float*)d_in[16];
    const float* bfc2       = (const float*)d_in[17];
    float* out = (float*)d_out;

    char* ws = (char*)d_ws;
    unsigned short* wq_t   = (unsigned short*)(ws);
    unsigned short* wp_t   = (unsigned short*)(ws + 294912);
    unsigned short* wfc1_t = (unsigned short*)(ws + 589824);
    unsigned short* wfc2_t = (unsigned short*)(ws + 1769472);
    float*          biasx  = (float*)(ws + 2949120);
    unsigned short* bufA   = (unsigned short*)(ws + 3080192);
    unsigned short* bufB   = (unsigned short*)(ws + 3080192 + 38535168);

    const int M = 50176;
    const float scale = 0.17677669529663687f;
    const int full_mlp = (ws_size >= (size_t)3080192 + 38535168 + 154140672);

    transpose_kernel<<<(384 * 384 + 255) / 256, 256, 0, stream>>>(Wqkv, wq_t, 384, 384, 1152);
    transpose_kernel<<<(384 * 384 + 255) / 256, 256, 0, stream>>>(Wproj, wp_t, 384, 384, 384);
    transpose_kernel<<<(384 * 1536 + 255) / 256, 256, 0, stream>>>(Wfc1, wfc1_t, 384, 1536, 1536);
    transpose_kernel<<<(1536 * 384 + 255) / 256, 256, 0, stream>>>(Wfc2, wfc2_t, 1536, 384, 384);
    bias_expand_kernel<<<(NHEAD * 2401 + 255) / 256, 256, 0, stream>>>(rel_index, bias_table, biasx);

    // LN1 -> windowed (bf16)
    ln_kernel<<<M, 64, 0, stream>>>(x, g1, b1, bufA, 1);
    // q = (hw @ Wq + bq) * scale -> bufB
    gemm_kernel<128, 0, 0, 1><<<3 * 392, 256, 0, stream>>>(bufA, wq_t, bqkv, nullptr, bufB,
                                                           M, 384, 384, scale, 3, 392);
    // attention -> bufA
    attn_kernel<<<16 * NHEAD * 4, 256, 0, stream>>>(bufB, kv, biasx, bufA);
    // proj + window_reverse + residual(x) -> d_out (fp32)
    gemm_kernel<128, 0, 1, 0><<<3 * 392, 256, 0, stream>>>(bufA, wp_t, bproj, x, d_out,
                                                           M, 384, 384, 1.f, 3, 392);
    // LN2
    ln_kernel<<<M, 64, 0, stream>>>(out, g2, b2, bufA, 0);

    if (full_mlp) {
        gemm_kernel<256, 1, 0, 1><<<6 * 392, 256, 0, stream>>>(bufA, wfc1_t, bfc1,
                                                               nullptr, bufB, M, 1536, 384, 1.f,
                                                               6, 392);
        gemm_kernel<128, 0, 0, 0><<<3 * 392, 256, 0, stream>>>(bufB, wfc2_t, bfc2,
                                                               out, out, M, 384, 1536, 1.f,
                                                               3, 392);
    } else {
        for (int c = 0; c < 4; c++) {
            size_t ro = (size_t)c * 12544;
            gemm_kernel<256, 1, 0, 1><<<6 * 98, 256, 0, stream>>>(bufA + ro * 384, wfc1_t, bfc1,
                                                                  nullptr, bufB, 12544, 1536, 384,
                                                                  1.f, 6, 98);
            gemm_kernel<128, 0, 0, 0><<<3 * 98, 256, 0, stream>>>(bufB, wfc2_t, bfc2,
                                                                  out + ro * 384, out + ro * 384,
                                                                  12544, 384, 1536, 1.f, 3, 98);
        }
    }
}